// Round 11
// baseline (363.315 us; speedup 1.0000x reference)
//
#include <hip/hip_runtime.h>
#include <hip/hip_bf16.h>

typedef __attribute__((ext_vector_type(8))) short short8;       // 8 x bf16 (4 VGPR)
typedef __attribute__((ext_vector_type(4))) float f32x4;        // MFMA acc / float4
typedef __attribute__((ext_vector_type(4))) unsigned short ushort4v;
typedef __attribute__((ext_vector_type(2))) unsigned int uint32x2;

__device__ __forceinline__ unsigned short f2bf(float f) {
    __hip_bfloat16 h = __float2bfloat16(f);
    return __builtin_bit_cast(unsigned short, h);
}
__device__ __forceinline__ unsigned int pack2(float a, float b) {
    return (unsigned int)f2bf(a) | ((unsigned int)f2bf(b) << 16);
}
__device__ __forceinline__ void gload_lds16(const void* g, void* l) {
    __builtin_amdgcn_global_load_lds((const __attribute__((address_space(1))) unsigned int*)g,
                                     (__attribute__((address_space(3))) unsigned int*)l, 16, 0, 0);
}

// ---------------- K0: w_qk fp32 -> bf16 row-major [256][512] ----------------
__global__ __launch_bounds__(256) void k0_cvt(const float* __restrict__ src,
                                              unsigned short* __restrict__ dst, int n) {
    int i = blockIdx.x * 256 + threadIdx.x;
    if (i < n) dst[i] = f2bf(src[i]);
}

// ---------------- K1: barrier-free 1-wave Q-GEMM + normalize ----------------
// grid: 4096 1-wave blocks. blk -> b = blk>>7; rem = blk&127; h = rem>>1; wc = rem&1.
// Wave computes D[256 ch][32 tok] for tokens x[b][:][h][wc*32 .. +31].
// A-frags (W) reg-loaded from L2; B-frags loaded DIRECTLY in fragment layout from x
// (lane (lo,hi), frag ni: 8 floats x[kt*32+hi*8+e][ni*16+lo]) and cvt'd in-register.
// No LDS, no __syncthreads. 1-deep prefetch; compiler places exact waitcnts.
__global__ __launch_bounds__(64, 2) void k1_qgemm(const float* __restrict__ x,
                                                  const unsigned short* __restrict__ wbf,
                                                  unsigned short* __restrict__ qn) {
    const int blk = blockIdx.x;
    const int b_  = blk >> 7;
    const int rem = blk & 127;
    const int h   = rem >> 1;
    const int wc  = rem & 1;
    const int win = b_ * 4 + (h >> 5) * 2 + wc;

    const int lane = threadIdx.x & 63;
    const int lo   = lane & 15;
    const int hi   = lane >> 4;

    const float* xbase = x + (size_t)b_ * 512 * 4096 + (size_t)h * 64 + wc * 32;

    f32x4 acc[16][2];
#pragma unroll
    for (int mi = 0; mi < 16; ++mi) {
        acc[mi][0] = (f32x4){0.f, 0.f, 0.f, 0.f};
        acc[mi][1] = (f32x4){0.f, 0.f, 0.f, 0.f};
    }

    short8 af[16];
    float brawA[16], brawB[16];

#define K1_LOADB(DST, KT)                                                           \
    {                                                                               \
        const float* bp_ = xbase + (size_t)((KT) * 32 + hi * 8) * 4096 + lo;        \
        _Pragma("unroll")                                                           \
        for (int e_ = 0; e_ < 8; ++e_) {                                            \
            DST[e_]     = bp_[(size_t)e_ * 4096];                                   \
            DST[8 + e_] = bp_[(size_t)e_ * 4096 + 16];                              \
        }                                                                           \
    }
#define K1_LOADA(KT)                                                                \
    {                                                                               \
        _Pragma("unroll")                                                           \
        for (int mi_ = 0; mi_ < 16; ++mi_)                                          \
            af[mi_] = *(const short8*)(wbf + (size_t)(mi_ * 16 + lo) * 512 + (KT) * 32 + hi * 8); \
    }
#define K1_ITER(KT, CUR, NXT)                                                       \
    {                                                                               \
        { const int ktn_ = ((KT) + 1 < 16) ? (KT) + 1 : 15; K1_LOADB(NXT, ktn_); }  \
        short8 bfr0, bfr1;                                                          \
        _Pragma("unroll")                                                           \
        for (int e_ = 0; e_ < 8; ++e_) {                                            \
            bfr0[e_] = (short)f2bf(CUR[e_]);                                        \
            bfr1[e_] = (short)f2bf(CUR[8 + e_]);                                    \
        }                                                                           \
        __builtin_amdgcn_s_setprio(1);                                              \
        _Pragma("unroll")                                                           \
        for (int mi_ = 0; mi_ < 16; ++mi_) {                                        \
            acc[mi_][0] = __builtin_amdgcn_mfma_f32_16x16x32_bf16(af[mi_], bfr0, acc[mi_][0], 0, 0, 0); \
            acc[mi_][1] = __builtin_amdgcn_mfma_f32_16x16x32_bf16(af[mi_], bfr1, acc[mi_][1], 0, 0, 0); \
        }                                                                           \
        __builtin_amdgcn_s_setprio(0);                                              \
        { const int ktn_ = ((KT) + 1 < 16) ? (KT) + 1 : 15; K1_LOADA(ktn_); }       \
    }

    // prologue
    K1_LOADB(brawA, 0);
    K1_LOADA(0);

    for (int kt2 = 0; kt2 < 8; ++kt2) {
        K1_ITER(kt2 * 2,     brawA, brawB);
        K1_ITER(kt2 * 2 + 1, brawB, brawA);
    }

    // ---- per-token norm over c (in-lane mi,r; cross-lane hi via shfl) ----
    char* qwin_out = (char*)qn + (size_t)win * (1024 * 256 * 2);
#pragma unroll
    for (int ni = 0; ni < 2; ++ni) {
        float s = 0.f;
#pragma unroll
        for (int mi = 0; mi < 16; ++mi)
#pragma unroll
            for (int r = 0; r < 4; ++r) s += acc[mi][ni][r] * acc[mi][ni][r];
        s += __shfl_xor(s, 16);
        s += __shfl_xor(s, 32);
        float inv = 1.f / (sqrtf(s) + 1e-6f);

        const int tok = ni * 16 + lo;
        const int rq  = (h & 31) * 32 + tok;
        const int swz = (rq & 7) << 4;
#pragma unroll
        for (int mi = 0; mi < 16; ++mi) {
            int c = mi * 16 + hi * 4;
            ushort4v o = {f2bf(acc[mi][ni][0] * inv), f2bf(acc[mi][ni][1] * inv),
                          f2bf(acc[mi][ni][2] * inv), f2bf(acc[mi][ni][3] * inv)};
            size_t off = ((size_t)rq * 512 + (size_t)(c * 2)) ^ (size_t)swz;
            *(ushort4v*)(qwin_out + off) = o;
        }
    }
}

// ---------------- K2: S^T = K Q^T, relu, packed P, PV (R8 verbatim) ----------------
// grid: 512 = 128 windows * 4 query-blocks (256 q each); bid&127 = window (XCD swizzle).
__global__ __launch_bounds__(256, 2) void k2_attn(const unsigned short* __restrict__ qn,
                                                  const float* __restrict__ v,
                                                  float* __restrict__ out) {
    const int g   = blockIdx.x;
    const int win = g & 127;
    const int qb  = g >> 7;
    const int b_  = win >> 2;
    const int h0  = ((win >> 1) & 1) << 5;
    const int w0  = (win & 1) << 5;

    __shared__ __align__(16) unsigned short lK[64 * 256];   // swizzled key image, 32 KB
    __shared__ __align__(16) unsigned short lP[256][72];    // P [q][key], 36 KB, wave-private rows
    __shared__ __align__(16) unsigned short lV[16][72];     // V^T [ch][key], row15 = ones

    const int tid  = threadIdx.x;
    const int lane = tid & 63;
    const int wv   = tid >> 6;
    const int lo   = lane & 15;
    const int hi   = lane >> 4;

    const char* qwin = (const char*)(qn + (size_t)win * 1024 * 256);
    const int qw0 = qb * 256 + wv * 64;

    short8 qa[4][8];
#pragma unroll
    for (int mi = 0; mi < 4; ++mi) {
        const int rq = qw0 + mi * 16 + lo;
        const size_t swz = (size_t)((rq & 7) << 4);
#pragma unroll
        for (int kc = 0; kc < 8; ++kc)
            qa[mi][kc] = *(const short8*)(qwin + (((size_t)rq * 512 + kc * 64 + hi * 16) ^ swz));
    }

    f32x4 accout[4];
#pragma unroll
    for (int t = 0; t < 4; ++t) accout[t] = (f32x4){0.f, 0.f, 0.f, 0.f};

    const float* vbase = v + (size_t)b_ * 15 * 4096 + (size_t)h0 * 64 + w0;
    char* lKb = (char*)lK;
    char* lPb = (char*)&lP[0][0];
    char* lVb = (char*)&lV[0][0];

    for (int chk = 0; chk < 16; ++chk) {
        const int kbase = chk << 6;
        __syncthreads();
        {
            const char* src = qwin + (size_t)kbase * 512;
#pragma unroll
            for (int r = 0; r < 8; ++r) {
                int idx = (r * 256 + tid) * 16;
                gload_lds16(src + idx, lKb + idx);
            }
        }
        {
            const int chn = tid & 15;
            const int kp  = tid >> 4;
            uint32x2 u;
            if (chn < 15) {
                int jk = kbase + kp * 4;
                const float* vp = vbase + (size_t)chn * 4096 + ((jk >> 5) * 64 + (jk & 31));
                f32x4 d = *(const f32x4*)vp;
                u[0] = pack2(d[0], d[1]);
                u[1] = pack2(d[2], d[3]);
            } else {
                u[0] = 0x3F803F80u;
                u[1] = 0x3F803F80u;
            }
            *(uint32x2*)(lVb + chn * 144 + kp * 8) = u;
        }
        __syncthreads();

#pragma unroll
        for (int ni = 0; ni < 4; ++ni) {
            f32x4 st[4];
#pragma unroll
            for (int mi = 0; mi < 4; ++mi) st[mi] = (f32x4){0.f, 0.f, 0.f, 0.f};
            __builtin_amdgcn_s_setprio(1);
#pragma unroll
            for (int kc = 0; kc < 8; ++kc) {
                const int row = ni * 16 + lo;
                const int off = ((row * 512) + kc * 64 + hi * 16) ^ ((row & 7) << 4);
                short8 kb = *(const short8*)(lKb + off);
#pragma unroll
                for (int mi = 0; mi < 4; ++mi)
                    st[mi] = __builtin_amdgcn_mfma_f32_16x16x32_bf16(kb, qa[mi][kc], st[mi], 0, 0, 0);
            }
            __builtin_amdgcn_s_setprio(0);
#pragma unroll
            for (int mi = 0; mi < 4; ++mi) {
                uint32x2 u;
                u[0] = pack2(fmaxf(st[mi][0], 0.f), fmaxf(st[mi][1], 0.f));
                u[1] = pack2(fmaxf(st[mi][2], 0.f), fmaxf(st[mi][3], 0.f));
                *(uint32x2*)(lPb + (wv * 64 + mi * 16 + lo) * 144 + ni * 32 + hi * 8) = u;
            }
        }

        __builtin_amdgcn_s_setprio(1);
#pragma unroll
        for (int t = 0; t < 4; ++t) {
#pragma unroll
            for (int ks = 0; ks < 2; ++ks) {
                short8 pa  = *(const short8*)(lPb + (wv * 64 + t * 16 + lo) * 144 + ks * 64 + hi * 16);
                short8 vbf = *(const short8*)(lVb + lo * 144 + ks * 64 + hi * 16);
                accout[t] = __builtin_amdgcn_mfma_f32_16x16x32_bf16(pa, vbf, accout[t], 0, 0, 0);
            }
        }
        __builtin_amdgcn_s_setprio(0);
    }

#pragma unroll
    for (int t = 0; t < 4; ++t) {
#pragma unroll
        for (int r = 0; r < 4; ++r) {
            float rs = __shfl(accout[t][r], (lane & 48) | 15);
            if (lo < 15) {
                int q = qw0 + t * 16 + hi * 4 + r;
                out[(size_t)(b_ * 15 + lo) * 4096 + (size_t)(h0 + (q >> 5)) * 64 + (w0 + (q & 31))] =
                    accout[t][r] / (rs + 1e-6f);
            }
        }
    }
}

extern "C" void kernel_launch(void* const* d_in, const int* in_sizes, int n_in,
                              void* d_out, int out_size, void* d_ws, size_t ws_size,
                              hipStream_t stream) {
    const float* x = (const float*)d_in[0];
    const float* v = (const float*)d_in[1];
    const float* w = (const float*)d_in[2];
    float* out = (float*)d_out;

    unsigned short* qn  = (unsigned short*)d_ws;                         // 64 MiB (swizzled)
    unsigned short* wbf = (unsigned short*)((char*)d_ws + (size_t)128 * 1024 * 256 * 2);  // 256 KiB

    k0_cvt<<<512, 256, 0, stream>>>(w, wbf, 256 * 512);
    k1_qgemm<<<4096, 64, 0, stream>>>(x, wbf, qn);
    k2_attn<<<512, 256, 0, stream>>>(qn, v, out);
}

// Round 12
// 151.032 us; speedup vs baseline: 2.4055x; 2.4055x over previous
//
#include <hip/hip_runtime.h>
#include <hip/hip_bf16.h>

typedef __attribute__((ext_vector_type(8))) short short8;       // 8 x bf16 (4 VGPR)
typedef __attribute__((ext_vector_type(4))) float f32x4;        // MFMA acc / float4
typedef __attribute__((ext_vector_type(2))) float f32x2;
typedef __attribute__((ext_vector_type(4))) unsigned short ushort4v;
typedef __attribute__((ext_vector_type(2))) unsigned int uint32x2;

__device__ __forceinline__ unsigned short f2bf(float f) {
    __hip_bfloat16 h = __float2bfloat16(f);
    return __builtin_bit_cast(unsigned short, h);
}
__device__ __forceinline__ unsigned int pack2(float a, float b) {
    return (unsigned int)f2bf(a) | ((unsigned int)f2bf(b) << 16);
}
__device__ __forceinline__ void gload_lds16(const void* g, void* l) {
    __builtin_amdgcn_global_load_lds((const __attribute__((address_space(1))) unsigned int*)g,
                                     (__attribute__((address_space(3))) unsigned int*)l, 16, 0, 0);
}

#define VMCNT(N) asm volatile("s_waitcnt vmcnt(" #N ")" ::: "memory")
#define LGKM0()  asm volatile("s_waitcnt lgkmcnt(0)" ::: "memory")

// ---------------- K0: W fp32 [256][512] -> wt bf16 tiled+bank-swizzled ----------------
// Slot (u=k>>3, c): byte off = ((u*256+c)*16) ^ ((u&3)<<4). Tile kt = bytes [kt*16384,+16384).
__global__ __launch_bounds__(256) void k0_wt(const float* __restrict__ w,
                                             unsigned short* __restrict__ wt) {
    int T = blockIdx.x * 256 + threadIdx.x;     // 0..16383 slots
    int c = T & 255, u = T >> 8;
    const float* s = w + c * 512 + u * 8;
    f32x4 a = *(const f32x4*)s;
    f32x4 b = *(const f32x4*)(s + 4);
    short8 o;
    o[0] = (short)f2bf(a[0]); o[1] = (short)f2bf(a[1]);
    o[2] = (short)f2bf(a[2]); o[3] = (short)f2bf(a[3]);
    o[4] = (short)f2bf(b[0]); o[5] = (short)f2bf(b[1]);
    o[6] = (short)f2bf(b[2]); o[7] = (short)f2bf(b[3]);
    size_t off = (size_t)(((u * 256 + c) * 16) ^ ((u & 3) << 4));
    *(short8*)((char*)wt + off) = o;
}

// ---------------- K1: Q-GEMM + normalize, row-contiguous blocks, coalesced qn store ----
// grid: 1024 = 32 b * 2 wh * 16 rb. Block covers 2 full h-rows x 64 w = 128 tokens,
// x bytes 512B-contiguous per channel. Main loop identical to R10 (counted prefetch).
// NEW epilogue: normalized bf16 staged in LDS (overlaid on dead lA/lB), then each
// 32-lane group stores one FULL 512B qn row (dwordx4, line-complete, no amplification).
// smem map: phase1: lA[2] @0 (2x16KB), lB[2] @32768 (2x10240B rows of 80B), nbuf @53248.
//           phase2: sQ @0, 128 rows x 512B, row f byte (c*2)^((f&7)<<4).
__global__ __launch_bounds__(256, 2) void k1_qgemm(const float* __restrict__ x,
                                                   const unsigned short* __restrict__ wt,
                                                   unsigned short* __restrict__ qn) {
    const int blk = blockIdx.x;
    const int b_  = blk >> 5;
    const int wh  = (blk >> 4) & 1;
    const int rb  = blk & 15;
    const int winbase = b_ * 4 + wh * 2;

    __shared__ __align__(16) char smem[65536];

    const int tid  = threadIdx.x;
    const int lane = tid & 63;
    const int wv   = tid >> 6;
    const int lo   = lane & 15;
    const int hi   = lane >> 4;

    f32x4 acc[4][8];
#pragma unroll
    for (int mi = 0; mi < 4; ++mi)
#pragma unroll
        for (int ni = 0; ni < 8; ++ni) acc[mi][ni] = (f32x4){0.f, 0.f, 0.f, 0.f};

    // x slab: rows wh*32 + 2rb, +1 (global h), all 64 w
    const float* xslab = x + (size_t)b_ * 512 * 4096 + (size_t)(wh * 32 + rb * 2) * 64;
    const int tp  = tid & 63;     // token-pair: tokens 2tp, 2tp+1 (f-order)
    const int cg  = tid >> 6;     // channel slab (= wv): channels cg*8 .. +7
    const int tt  = tp * 2;
    const float* xpbase = xslab + (size_t)(cg * 8) * 4096 + tt;

    f32x2 bregs[8];

#define K1_ISSUE_A(KT, BUF)                                                        \
    {                                                                              \
        const char* src_ = (const char*)wt + (size_t)(KT) * 16384;                 \
        char* dst_ = smem + (BUF) * 16384;                                         \
        _Pragma("unroll")                                                          \
        for (int r_ = 0; r_ < 4; ++r_) {                                           \
            int idx_ = (r_ * 256 + tid) * 16;                                      \
            gload_lds16(src_ + idx_, dst_ + idx_);                                 \
        }                                                                          \
    }
#define K1_LOAD_B(KT)                                                              \
    {                                                                              \
        const float* xp_ = xpbase + (size_t)(KT) * 32 * 4096;                      \
        _Pragma("unroll")                                                          \
        for (int i_ = 0; i_ < 8; ++i_) bregs[i_] = *(const f32x2*)(xp_ + (size_t)i_ * 4096); \
    }
#define K1_WRITE_B(BUF)                                                            \
    {                                                                              \
        short8 v0_, v1_;                                                           \
        _Pragma("unroll")                                                          \
        for (int i_ = 0; i_ < 8; ++i_) {                                           \
            v0_[i_] = (short)f2bf(bregs[i_][0]);                                   \
            v1_[i_] = (short)f2bf(bregs[i_][1]);                                   \
        }                                                                          \
        char* lb_ = smem + 32768 + (BUF) * 10240;                                  \
        *(short8*)(lb_ + tt * 80 + cg * 16)       = v0_;                           \
        *(short8*)(lb_ + (tt + 1) * 80 + cg * 16) = v1_;                           \
    }

    // prologue
    K1_ISSUE_A(0, 0);
    K1_LOAD_B(0);
    K1_WRITE_B(0);      // auto vmcnt(0): drains DMA(0) too (prologue only)
    K1_LOAD_B(1);
    LGKM0();
    __builtin_amdgcn_s_barrier();

    for (int kt = 0; kt < 16; ++kt) {
        const int b = kt & 1;
        // 1. DMA next A tile into lA[b^1]
        {
            const int ktn = (kt + 1 < 16) ? kt + 1 : 15;
            K1_ISSUE_A(ktn, b ^ 1);
        }
        // 2. compute current tile
        short8 af[4], bfr[8];
#pragma unroll
        for (int mi = 0; mi < 4; ++mi) {
            int base = (hi * 256 + wv * 64 + mi * 16 + lo) * 16;   // bytes
            af[mi] = *(const short8*)(smem + b * 16384 + (base ^ ((hi & 3) << 4)));
        }
#pragma unroll
        for (int ni = 0; ni < 8; ++ni)
            bfr[ni] = *(const short8*)(smem + 32768 + b * 10240 + (ni * 16 + lo) * 80 + hi * 16);
        __builtin_amdgcn_s_setprio(1);
#pragma unroll
        for (int mi = 0; mi < 4; ++mi)
#pragma unroll
            for (int ni = 0; ni < 8; ++ni)
                acc[mi][ni] = __builtin_amdgcn_mfma_f32_16x16x32_bf16(af[mi], bfr[ni], acc[mi][ni], 0, 0, 0);
        __builtin_amdgcn_s_setprio(0);
        // 3. write next B (bregs ~1 iter old; auto-wait = vmcnt(4), DMA stays in flight)
        K1_WRITE_B(b ^ 1);
        // 4. pin VMEM order across the next issue
        __builtin_amdgcn_sched_barrier(0);
        // 5. issue B loads for kt+2
        {
            const int ktn2 = (kt + 2 < 16) ? kt + 2 : 15;
            K1_LOAD_B(ktn2);
        }
        // 6. wait: 4 DMA done (8 younger B-loads in flight); publish lB writes
        VMCNT(8);
        LGKM0();
        __builtin_amdgcn_s_barrier();
    }
    VMCNT(0);   // drain tail prefetches

    // ---- per-token norm over c ----
    float part[8];
#pragma unroll
    for (int ni = 0; ni < 8; ++ni) {
        float s = 0.f;
#pragma unroll
        for (int mi = 0; mi < 4; ++mi)
#pragma unroll
            for (int r = 0; r < 4; ++r) s += acc[mi][ni][r] * acc[mi][ni][r];
        s += __shfl_xor(s, 16);
        s += __shfl_xor(s, 32);
        part[ni] = s;
    }
    if (hi == 0) {
#pragma unroll
        for (int ni = 0; ni < 8; ++ni)
            *(float*)(smem + 53248 + (wv * 128 + ni * 16 + lo) * 4) = part[ni];
    }
    __syncthreads();

    float inv[8];
#pragma unroll
    for (int ni = 0; ni < 8; ++ni) {
        const int tl = ni * 16 + lo;
        float s = *(const float*)(smem + 53248 + (0 * 128 + tl) * 4)
                + *(const float*)(smem + 53248 + (1 * 128 + tl) * 4)
                + *(const float*)(smem + 53248 + (2 * 128 + tl) * 4)
                + *(const float*)(smem + 53248 + (3 * 128 + tl) * 4);
        inv[ni] = 1.f / (sqrtf(s) + 1e-6f);
    }
    __syncthreads();   // nbuf consumed; smem now reusable as sQ

    // stage normalized bf16 into sQ (row f, byte (c*2)^((f&7)<<4)) — ~2-way conflicts
#pragma unroll
    for (int ni = 0; ni < 8; ++ni) {
        const int f    = ni * 16 + lo;
        const int swzf = (f & 7) << 4;
#pragma unroll
        for (int mi = 0; mi < 4; ++mi) {
            const int c2 = wv * 128 + mi * 32 + hi * 8;   // channel byte offset
            uint32x2 u;
            u[0] = pack2(acc[mi][ni][0] * inv[ni], acc[mi][ni][1] * inv[ni]);
            u[1] = pack2(acc[mi][ni][2] * inv[ni], acc[mi][ni][3] * inv[ni]);
            *(uint32x2*)(smem + f * 512 + (c2 ^ swzf)) = u;
        }
    }
    __syncthreads();

    // coalesced store: each 32-lane group emits one full 512B qn row (line-complete)
#pragma unroll
    for (int it = 0; it < 16; ++it) {
        const int chunk = it * 256 + tid;        // 0..4095 (16B units)
        const int f     = chunk >> 5;
        const int c16   = (chunk & 31) * 16;
        f32x4 d = *(const f32x4*)(smem + f * 512 + (c16 ^ ((f & 7) << 4)));
        const int ww  = (f >> 5) & 1;
        const int rho = f >> 6;
        const int rq  = rb * 64 + rho * 32 + (f & 31);
        char* qw = (char*)qn + (size_t)(winbase + ww) * (1024 * 256 * 2);
        *(f32x4*)(qw + (size_t)rq * 512 + (c16 ^ ((rq & 7) << 4))) = d;
    }
}

// ---------------- K2: S^T = K Q^T, relu, packed P, PV (R8/R10 verbatim) ----------------
// grid: 512 = 128 windows * 4 query-blocks (256 q each); bid&127 = window (XCD swizzle).
__global__ __launch_bounds__(256, 2) void k2_attn(const unsigned short* __restrict__ qn,
                                                  const float* __restrict__ v,
                                                  float* __restrict__ out) {
    const int g   = blockIdx.x;
    const int win = g & 127;
    const int qb  = g >> 7;
    const int b_  = win >> 2;
    const int h0  = ((win >> 1) & 1) << 5;
    const int w0  = (win & 1) << 5;

    __shared__ __align__(16) unsigned short lK[64 * 256];   // swizzled key image, 32 KB
    __shared__ __align__(16) unsigned short lP[256][72];    // P [q][key], 36 KB, wave-private rows
    __shared__ __align__(16) unsigned short lV[16][72];     // V^T [ch][key], row15 = ones

    const int tid  = threadIdx.x;
    const int lane = tid & 63;
    const int wv   = tid >> 6;
    const int lo   = lane & 15;
    const int hi   = lane >> 4;

    const char* qwin = (const char*)(qn + (size_t)win * 1024 * 256);
    const int qw0 = qb * 256 + wv * 64;

    short8 qa[4][8];
#pragma unroll
    for (int mi = 0; mi < 4; ++mi) {
        const int rq = qw0 + mi * 16 + lo;
        const size_t swz = (size_t)((rq & 7) << 4);
#pragma unroll
        for (int kc = 0; kc < 8; ++kc)
            qa[mi][kc] = *(const short8*)(qwin + (((size_t)rq * 512 + kc * 64 + hi * 16) ^ swz));
    }

    f32x4 accout[4];
#pragma unroll
    for (int t = 0; t < 4; ++t) accout[t] = (f32x4){0.f, 0.f, 0.f, 0.f};

    const float* vbase = v + (size_t)b_ * 15 * 4096 + (size_t)h0 * 64 + w0;
    char* lKb = (char*)lK;
    char* lPb = (char*)&lP[0][0];
    char* lVb = (char*)&lV[0][0];

    for (int chk = 0; chk < 16; ++chk) {
        const int kbase = chk << 6;
        __syncthreads();
        {
            const char* src = qwin + (size_t)kbase * 512;
#pragma unroll
            for (int r = 0; r < 8; ++r) {
                int idx = (r * 256 + tid) * 16;
                gload_lds16(src + idx, lKb + idx);
            }
        }
        {
            const int chn = tid & 15;
            const int kp  = tid >> 4;
            uint32x2 u;
            if (chn < 15) {
                int jk = kbase + kp * 4;
                const float* vp = vbase + (size_t)chn * 4096 + ((jk >> 5) * 64 + (jk & 31));
                f32x4 d = *(const f32x4*)vp;
                u[0] = pack2(d[0], d[1]);
                u[1] = pack2(d[2], d[3]);
            } else {
                u[0] = 0x3F803F80u;
                u[1] = 0x3F803F80u;
            }
            *(uint32x2*)(lVb + chn * 144 + kp * 8) = u;
        }
        __syncthreads();

#pragma unroll
        for (int ni = 0; ni < 4; ++ni) {
            f32x4 st[4];
#pragma unroll
            for (int mi = 0; mi < 4; ++mi) st[mi] = (f32x4){0.f, 0.f, 0.f, 0.f};
            __builtin_amdgcn_s_setprio(1);
#pragma unroll
            for (int kc = 0; kc < 8; ++kc) {
                const int row = ni * 16 + lo;
                const int off = ((row * 512) + kc * 64 + hi * 16) ^ ((row & 7) << 4);
                short8 kb = *(const short8*)(lKb + off);
#pragma unroll
                for (int mi = 0; mi < 4; ++mi)
                    st[mi] = __builtin_amdgcn_mfma_f32_16x16x32_bf16(kb, qa[mi][kc], st[mi], 0, 0, 0);
            }
            __builtin_amdgcn_s_setprio(0);
#pragma unroll
            for (int mi = 0; mi < 4; ++mi) {
                uint32x2 u;
                u[0] = pack2(fmaxf(st[mi][0], 0.f), fmaxf(st[mi][1], 0.f));
                u[1] = pack2(fmaxf(st[mi][2], 0.f), fmaxf(st[mi][3], 0.f));
                *(uint32x2*)(lPb + (wv * 64 + mi * 16 + lo) * 144 + ni * 32 + hi * 8) = u;
            }
        }

        __builtin_amdgcn_s_setprio(1);
#pragma unroll
        for (int t = 0; t < 4; ++t) {
#pragma unroll
            for (int ks = 0; ks < 2; ++ks) {
                short8 pa  = *(const short8*)(lPb + (wv * 64 + t * 16 + lo) * 144 + ks * 64 + hi * 16);
                short8 vbf = *(const short8*)(lVb + lo * 144 + ks * 64 + hi * 16);
                accout[t] = __builtin_amdgcn_mfma_f32_16x16x32_bf16(pa, vbf, accout[t], 0, 0, 0);
            }
        }
        __builtin_amdgcn_s_setprio(0);
    }

#pragma unroll
    for (int t = 0; t < 4; ++t) {
#pragma unroll
        for (int r = 0; r < 4; ++r) {
            float rs = __shfl(accout[t][r], (lane & 48) | 15);
            if (lo < 15) {
                int q = qw0 + t * 16 + hi * 4 + r;
                out[(size_t)(b_ * 15 + lo) * 4096 + (size_t)(h0 + (q >> 5)) * 64 + (w0 + (q & 31))] =
                    accout[t][r] / (rs + 1e-6f);
            }
        }
    }
}

extern "C" void kernel_launch(void* const* d_in, const int* in_sizes, int n_in,
                              void* d_out, int out_size, void* d_ws, size_t ws_size,
                              hipStream_t stream) {
    const float* x = (const float*)d_in[0];
    const float* v = (const float*)d_in[1];
    const float* w = (const float*)d_in[2];
    float* out = (float*)d_out;

    unsigned short* qn = (unsigned short*)d_ws;                          // 64 MiB (swizzled)
    unsigned short* wt = (unsigned short*)((char*)d_ws + (size_t)128 * 1024 * 256 * 2);  // 256 KiB tiled W

    k0_wt<<<64, 256, 0, stream>>>(w, wt);
    k1_qgemm<<<1024, 256, 0, stream>>>(x, wt, qn);
    k2_attn<<<512, 256, 0, stream>>>(qn, v, out);
}

// Round 13
// 127.804 us; speedup vs baseline: 2.8427x; 1.1817x over previous
//
#include <hip/hip_runtime.h>
#include <hip/hip_bf16.h>

typedef __attribute__((ext_vector_type(8))) short short8;       // 8 x bf16 (4 VGPR)
typedef __attribute__((ext_vector_type(4))) float f32x4;        // MFMA acc / float4
typedef __attribute__((ext_vector_type(2))) float f32x2;
typedef __attribute__((ext_vector_type(4))) unsigned short ushort4v;
typedef __attribute__((ext_vector_type(2))) unsigned int uint32x2;

__device__ __forceinline__ unsigned short f2bf(float f) {
    __hip_bfloat16 h = __float2bfloat16(f);
    return __builtin_bit_cast(unsigned short, h);
}
__device__ __forceinline__ unsigned int pack2(float a, float b) {
    return (unsigned int)f2bf(a) | ((unsigned int)f2bf(b) << 16);
}
__device__ __forceinline__ unsigned int pk_fp8x4(float a0, float a1, float a2, float a3) {
    int v = 0;
    v = __builtin_amdgcn_cvt_pk_fp8_f32(a0, a1, v, false);   // bytes 0,1
    v = __builtin_amdgcn_cvt_pk_fp8_f32(a2, a3, v, true);    // bytes 2,3
    return (unsigned int)v;
}
__device__ __forceinline__ void gload_lds16(const void* g, void* l) {
    __builtin_amdgcn_global_load_lds((const __attribute__((address_space(1))) unsigned int*)g,
                                     (__attribute__((address_space(3))) unsigned int*)l, 16, 0, 0);
}

#define VMCNT(N) asm volatile("s_waitcnt vmcnt(" #N ")" ::: "memory")
#define LGKM0()  asm volatile("s_waitcnt lgkmcnt(0)" ::: "memory")

// ---------------- K0: W fp32 [256][512] -> wt bf16 tiled+bank-swizzled (R12 verbatim) ----
__global__ __launch_bounds__(256) void k0_wt(const float* __restrict__ w,
                                             unsigned short* __restrict__ wt) {
    int T = blockIdx.x * 256 + threadIdx.x;     // 0..16383 slots
    int c = T & 255, u = T >> 8;
    const float* s = w + c * 512 + u * 8;
    f32x4 a = *(const f32x4*)s;
    f32x4 b = *(const f32x4*)(s + 4);
    short8 o;
    o[0] = (short)f2bf(a[0]); o[1] = (short)f2bf(a[1]);
    o[2] = (short)f2bf(a[2]); o[3] = (short)f2bf(a[3]);
    o[4] = (short)f2bf(b[0]); o[5] = (short)f2bf(b[1]);
    o[6] = (short)f2bf(b[2]); o[7] = (short)f2bf(b[3]);
    size_t off = (size_t)(((u * 256 + c) * 16) ^ ((u & 3) << 4));
    *(short8*)((char*)wt + off) = o;
}

// ---------------- K1: Q-GEMM + normalize; qn output = fp8 e4m3, 256B rows, swizzled ----
// Main loop = R12 verbatim. Epilogue: normalize -> fp8 -> LDS stage -> coalesced rows.
// qn row rq byte layout: ch c at (c) ^ ((rq&3)<<4); window stride 256 KB.
__global__ __launch_bounds__(256, 2) void k1_qgemm(const float* __restrict__ x,
                                                   const unsigned short* __restrict__ wt,
                                                   unsigned char* __restrict__ qn) {
    const int blk = blockIdx.x;
    const int b_  = blk >> 5;
    const int wh  = (blk >> 4) & 1;
    const int rb  = blk & 15;
    const int winbase = b_ * 4 + wh * 2;

    __shared__ __align__(16) char smem[65536];

    const int tid  = threadIdx.x;
    const int lane = tid & 63;
    const int wv   = tid >> 6;
    const int lo   = lane & 15;
    const int hi   = lane >> 4;

    f32x4 acc[4][8];
#pragma unroll
    for (int mi = 0; mi < 4; ++mi)
#pragma unroll
        for (int ni = 0; ni < 8; ++ni) acc[mi][ni] = (f32x4){0.f, 0.f, 0.f, 0.f};

    const float* xslab = x + (size_t)b_ * 512 * 4096 + (size_t)(wh * 32 + rb * 2) * 64;
    const int tp  = tid & 63;
    const int cg  = tid >> 6;
    const int tt  = tp * 2;
    const float* xpbase = xslab + (size_t)(cg * 8) * 4096 + tt;

    f32x2 bregs[8];

#define K1_ISSUE_A(KT, BUF)                                                        \
    {                                                                              \
        const char* src_ = (const char*)wt + (size_t)(KT) * 16384;                 \
        char* dst_ = smem + (BUF) * 16384;                                         \
        _Pragma("unroll")                                                          \
        for (int r_ = 0; r_ < 4; ++r_) {                                           \
            int idx_ = (r_ * 256 + tid) * 16;                                      \
            gload_lds16(src_ + idx_, dst_ + idx_);                                 \
        }                                                                          \
    }
#define K1_LOAD_B(KT)                                                              \
    {                                                                              \
        const float* xp_ = xpbase + (size_t)(KT) * 32 * 4096;                      \
        _Pragma("unroll")                                                          \
        for (int i_ = 0; i_ < 8; ++i_) bregs[i_] = *(const f32x2*)(xp_ + (size_t)i_ * 4096); \
    }
#define K1_WRITE_B(BUF)                                                            \
    {                                                                              \
        short8 v0_, v1_;                                                           \
        _Pragma("unroll")                                                          \
        for (int i_ = 0; i_ < 8; ++i_) {                                           \
            v0_[i_] = (short)f2bf(bregs[i_][0]);                                   \
            v1_[i_] = (short)f2bf(bregs[i_][1]);                                   \
        }                                                                          \
        char* lb_ = smem + 32768 + (BUF) * 10240;                                  \
        *(short8*)(lb_ + tt * 80 + cg * 16)       = v0_;                           \
        *(short8*)(lb_ + (tt + 1) * 80 + cg * 16) = v1_;                           \
    }

    // prologue
    K1_ISSUE_A(0, 0);
    K1_LOAD_B(0);
    K1_WRITE_B(0);
    K1_LOAD_B(1);
    LGKM0();
    __builtin_amdgcn_s_barrier();

    for (int kt = 0; kt < 16; ++kt) {
        const int b = kt & 1;
        {
            const int ktn = (kt + 1 < 16) ? kt + 1 : 15;
            K1_ISSUE_A(ktn, b ^ 1);
        }
        short8 af[4], bfr[8];
#pragma unroll
        for (int mi = 0; mi < 4; ++mi) {
            int base = (hi * 256 + wv * 64 + mi * 16 + lo) * 16;
            af[mi] = *(const short8*)(smem + b * 16384 + (base ^ ((hi & 3) << 4)));
        }
#pragma unroll
        for (int ni = 0; ni < 8; ++ni)
            bfr[ni] = *(const short8*)(smem + 32768 + b * 10240 + (ni * 16 + lo) * 80 + hi * 16);
        __builtin_amdgcn_s_setprio(1);
#pragma unroll
        for (int mi = 0; mi < 4; ++mi)
#pragma unroll
            for (int ni = 0; ni < 8; ++ni)
                acc[mi][ni] = __builtin_amdgcn_mfma_f32_16x16x32_bf16(af[mi], bfr[ni], acc[mi][ni], 0, 0, 0);
        __builtin_amdgcn_s_setprio(0);
        K1_WRITE_B(b ^ 1);
        __builtin_amdgcn_sched_barrier(0);
        {
            const int ktn2 = (kt + 2 < 16) ? kt + 2 : 15;
            K1_LOAD_B(ktn2);
        }
        VMCNT(8);
        LGKM0();
        __builtin_amdgcn_s_barrier();
    }
    VMCNT(0);

    // ---- per-token norm over c ----
    float part[8];
#pragma unroll
    for (int ni = 0; ni < 8; ++ni) {
        float s = 0.f;
#pragma unroll
        for (int mi = 0; mi < 4; ++mi)
#pragma unroll
            for (int r = 0; r < 4; ++r) s += acc[mi][ni][r] * acc[mi][ni][r];
        s += __shfl_xor(s, 16);
        s += __shfl_xor(s, 32);
        part[ni] = s;
    }
    if (hi == 0) {
#pragma unroll
        for (int ni = 0; ni < 8; ++ni)
            *(float*)(smem + 53248 + (wv * 128 + ni * 16 + lo) * 4) = part[ni];
    }
    __syncthreads();

    float inv[8];
#pragma unroll
    for (int ni = 0; ni < 8; ++ni) {
        const int tl = ni * 16 + lo;
        float s = *(const float*)(smem + 53248 + (0 * 128 + tl) * 4)
                + *(const float*)(smem + 53248 + (1 * 128 + tl) * 4)
                + *(const float*)(smem + 53248 + (2 * 128 + tl) * 4)
                + *(const float*)(smem + 53248 + (3 * 128 + tl) * 4);
        inv[ni] = 1.f / (sqrtf(s) + 1e-6f);
    }

    // stage normalized fp8 into sQ @smem[0..32K): row f (256B), byte c ^ ((f&3)<<4)
#pragma unroll
    for (int ni = 0; ni < 8; ++ni) {
        const int f    = ni * 16 + lo;
        const int swzf = (f & 3) << 4;
#pragma unroll
        for (int mi = 0; mi < 4; ++mi) {
            const int c = wv * 64 + mi * 16 + hi * 4;
            unsigned int u = pk_fp8x4(acc[mi][ni][0] * inv[ni], acc[mi][ni][1] * inv[ni],
                                      acc[mi][ni][2] * inv[ni], acc[mi][ni][3] * inv[ni]);
            *(unsigned int*)(smem + f * 256 + (c ^ swzf)) = u;
        }
    }
    __syncthreads();

    // coalesced store: 32 KB, 16B units; each row (256B) line-complete
#pragma unroll
    for (int it = 0; it < 8; ++it) {
        const int unit = it * 256 + tid;         // 0..2047
        const int f    = unit >> 4;
        const int c16  = (unit & 15) * 16;
        f32x4 d = *(const f32x4*)(smem + f * 256 + (c16 ^ ((f & 3) << 4)));
        const int ww  = (f >> 5) & 1;
        const int rho = f >> 6;
        const int rq  = rb * 64 + rho * 32 + (f & 31);
        char* qw = (char*)qn + (size_t)(winbase + ww) * (1024 * 256);
        *(f32x4*)(qw + (size_t)rq * 256 + (c16 ^ ((rq & 3) << 4))) = d;
    }
}

// ---------------- K2: S^T via fp8 MFMA, relu, packed bf16 P, PV (structure = R12) ----
// grid: 512 = 128 windows * 4 query-blocks (256 q); bid&127 = window (XCD swizzle).
__global__ __launch_bounds__(256, 2) void k2_attn(const unsigned char* __restrict__ qn,
                                                  const float* __restrict__ v,
                                                  float* __restrict__ out) {
    const int g   = blockIdx.x;
    const int win = g & 127;
    const int qb  = g >> 7;
    const int b_  = win >> 2;
    const int h0  = ((win >> 1) & 1) << 5;
    const int w0  = (win & 1) << 5;

    __shared__ __align__(16) char lK[64 * 256];             // fp8 key image, 16 KB
    __shared__ __align__(16) unsigned short lP[256][72];    // P bf16 [q][key], 36 KB
    __shared__ __align__(16) unsigned short lV[16][72];     // V^T [ch][key], row15 = ones

    const int tid  = threadIdx.x;
    const int lane = tid & 63;
    const int wv   = tid >> 6;
    const int lo   = lane & 15;
    const int hi   = lane >> 4;

    const unsigned char* qwin = qn + (size_t)win * (1024 * 256);
    const int qw0 = qb * 256 + wv * 64;

    // hoisted Q fragments (fp8, 2 VGPR each)
    long qa8[4][8];
#pragma unroll
    for (int mi = 0; mi < 4; ++mi) {
        const int rq = qw0 + mi * 16 + lo;
        const size_t swz = (size_t)((rq & 3) << 4);
#pragma unroll
        for (int kc = 0; kc < 8; ++kc)
            qa8[mi][kc] = *(const long*)(qwin + (((size_t)rq * 256 + kc * 32 + hi * 8) ^ swz));
    }

    f32x4 accout[4];
#pragma unroll
    for (int t = 0; t < 4; ++t) accout[t] = (f32x4){0.f, 0.f, 0.f, 0.f};

    const float* vbase = v + (size_t)b_ * 15 * 4096 + (size_t)h0 * 64 + w0;
    char* lKb = (char*)lK;
    char* lPb = (char*)&lP[0][0];
    char* lVb = (char*)&lV[0][0];

    for (int chk = 0; chk < 16; ++chk) {
        const int kbase = chk << 6;
        __syncthreads();
        // stage keys: linear 16 KB DMA from swizzled fp8 qn
        {
            const char* src = (const char*)qwin + (size_t)kbase * 256;
#pragma unroll
            for (int r = 0; r < 4; ++r) {
                int idx = (r * 256 + tid) * 16;
                gload_lds16(src + idx, lKb + idx);
            }
        }
        // stage V^T 16x64 (ch 15 = ones)
        {
            const int chn = tid & 15;
            const int kp  = tid >> 4;
            uint32x2 u;
            if (chn < 15) {
                int jk = kbase + kp * 4;
                const float* vp = vbase + (size_t)chn * 4096 + ((jk >> 5) * 64 + (jk & 31));
                f32x4 d = *(const f32x4*)vp;
                u[0] = pack2(d[0], d[1]);
                u[1] = pack2(d[2], d[3]);
            } else {
                u[0] = 0x3F803F80u;
                u[1] = 0x3F803F80u;
            }
            *(uint32x2*)(lVb + chn * 144 + kp * 8) = u;
        }
        __syncthreads();

        // S^T: D = mfma_fp8(A=kb, B=qa8) -> lane: col=q(lo), rows=key(4hi+r)
#pragma unroll
        for (int ni = 0; ni < 4; ++ni) {
            f32x4 st[4];
#pragma unroll
            for (int mi = 0; mi < 4; ++mi) st[mi] = (f32x4){0.f, 0.f, 0.f, 0.f};
            __builtin_amdgcn_s_setprio(1);
#pragma unroll
            for (int kc = 0; kc < 8; ++kc) {
                const int row = ni * 16 + lo;
                const int off = ((row * 256) + kc * 32 + hi * 8) ^ ((row & 3) << 4);
                long kb = *(const long*)(lKb + off);
#pragma unroll
                for (int mi = 0; mi < 4; ++mi)
                    st[mi] = __builtin_amdgcn_mfma_f32_16x16x32_fp8_fp8(kb, qa8[mi][kc], st[mi], 0, 0, 0);
            }
            __builtin_amdgcn_s_setprio(0);
#pragma unroll
            for (int mi = 0; mi < 4; ++mi) {
                uint32x2 u;
                u[0] = pack2(fmaxf(st[mi][0], 0.f), fmaxf(st[mi][1], 0.f));
                u[1] = pack2(fmaxf(st[mi][2], 0.f), fmaxf(st[mi][3], 0.f));
                *(uint32x2*)(lPb + (wv * 64 + mi * 16 + lo) * 144 + ni * 32 + hi * 8) = u;
            }
        }

        // PV: per wave 64q, N=16 (15 v-ch + rowsum), K=64 (wave-private lP rows)
        __builtin_amdgcn_s_setprio(1);
#pragma unroll
        for (int t = 0; t < 4; ++t) {
#pragma unroll
            for (int ks = 0; ks < 2; ++ks) {
                short8 pa  = *(const short8*)(lPb + (wv * 64 + t * 16 + lo) * 144 + ks * 64 + hi * 16);
                short8 vbf = *(const short8*)(lVb + lo * 144 + ks * 64 + hi * 16);
                accout[t] = __builtin_amdgcn_mfma_f32_16x16x32_bf16(pa, vbf, accout[t], 0, 0, 0);
            }
        }
        __builtin_amdgcn_s_setprio(0);
    }

    // epilogue: divide by rowsum (ch 15) and store
#pragma unroll
    for (int t = 0; t < 4; ++t) {
#pragma unroll
        for (int r = 0; r < 4; ++r) {
            float rs = __shfl(accout[t][r], (lane & 48) | 15);
            if (lo < 15) {
                int q = qw0 + t * 16 + hi * 4 + r;
                out[(size_t)(b_ * 15 + lo) * 4096 + (size_t)(h0 + (q >> 5)) * 64 + (w0 + (q & 31))] =
                    accout[t][r] / (rs + 1e-6f);
            }
        }
    }
}

extern "C" void kernel_launch(void* const* d_in, const int* in_sizes, int n_in,
                              void* d_out, int out_size, void* d_ws, size_t ws_size,
                              hipStream_t stream) {
    const float* x = (const float*)d_in[0];
    const float* v = (const float*)d_in[1];
    const float* w = (const float*)d_in[2];
    float* out = (float*)d_out;

    unsigned char*  qn = (unsigned char*)d_ws;                           // 32 MiB fp8 (swizzled)
    unsigned short* wt = (unsigned short*)((char*)d_ws + (size_t)32 * 1024 * 1024);  // 256 KiB tiled W

    k0_wt<<<64, 256, 0, stream>>>(w, wt);
    k1_qgemm<<<1024, 256, 0, stream>>>(x, wt, qn);
    k2_attn<<<512, 256, 0, stream>>>(qn, v, out);
}

// Round 14
// 125.985 us; speedup vs baseline: 2.8838x; 1.0144x over previous
//
#include <hip/hip_runtime.h>
#include <hip/hip_bf16.h>

typedef __attribute__((ext_vector_type(8))) short short8;       // 8 x bf16 (4 VGPR)
typedef __attribute__((ext_vector_type(4))) float f32x4;        // MFMA acc / float4
typedef __attribute__((ext_vector_type(2))) float f32x2;
typedef __attribute__((ext_vector_type(4))) unsigned short ushort4v;
typedef __attribute__((ext_vector_type(2))) unsigned int uint32x2;

__device__ __forceinline__ unsigned short f2bf(float f) {
    __hip_bfloat16 h = __float2bfloat16(f);
    return __builtin_bit_cast(unsigned short, h);
}
__device__ __forceinline__ unsigned int pack2(float a, float b) {
    return (unsigned int)f2bf(a) | ((unsigned int)f2bf(b) << 16);
}
__device__ __forceinline__ unsigned int pk_fp8x4(float a0, float a1, float a2, float a3) {
    int v = 0;
    v = __builtin_amdgcn_cvt_pk_fp8_f32(a0, a1, v, false);   // bytes 0,1
    v = __builtin_amdgcn_cvt_pk_fp8_f32(a2, a3, v, true);    // bytes 2,3
    return (unsigned int)v;
}
__device__ __forceinline__ void gload_lds16(const void* g, void* l) {
    __builtin_amdgcn_global_load_lds((const __attribute__((address_space(1))) unsigned int*)g,
                                     (__attribute__((address_space(3))) unsigned int*)l, 16, 0, 0);
}

#define VMCNT(N) asm volatile("s_waitcnt vmcnt(" #N ")" ::: "memory")
#define LGKM0()  asm volatile("s_waitcnt lgkmcnt(0)" ::: "memory")

// ---------------- K0: W fp32 [256][512] -> wt bf16 tiled+bank-swizzled (R13 verbatim) ----
__global__ __launch_bounds__(256) void k0_wt(const float* __restrict__ w,
                                             unsigned short* __restrict__ wt) {
    int T = blockIdx.x * 256 + threadIdx.x;     // 0..16383 slots
    int c = T & 255, u = T >> 8;
    const float* s = w + c * 512 + u * 8;
    f32x4 a = *(const f32x4*)s;
    f32x4 b = *(const f32x4*)(s + 4);
    short8 o;
    o[0] = (short)f2bf(a[0]); o[1] = (short)f2bf(a[1]);
    o[2] = (short)f2bf(a[2]); o[3] = (short)f2bf(a[3]);
    o[4] = (short)f2bf(b[0]); o[5] = (short)f2bf(b[1]);
    o[6] = (short)f2bf(b[2]); o[7] = (short)f2bf(b[3]);
    size_t off = (size_t)(((u * 256 + c) * 16) ^ ((u & 3) << 4));
    *(short8*)((char*)wt + off) = o;
}

// ---------------- K1: Q-GEMM + normalize; 8 VMEM instr/iter (4x f32x4 B + 4 DMA A) ----
// grid: 1024 = 32 b * 2 wh * 16 rb; block covers 2 full h-rows x 64 w = 128 tokens
// (x bytes 512B-contiguous per channel). B-staging: thread (tq=tid&31, cs=tid>>5) loads
// f32x4 (4 tokens) for 4 channels -> 4 b64 LDS writes. qn out = fp8 swizzled (R13).
__global__ __launch_bounds__(256, 2) void k1_qgemm(const float* __restrict__ x,
                                                   const unsigned short* __restrict__ wt,
                                                   unsigned char* __restrict__ qn) {
    const int blk = blockIdx.x;
    const int b_  = blk >> 5;
    const int wh  = (blk >> 4) & 1;
    const int rb  = blk & 15;
    const int winbase = b_ * 4 + wh * 2;

    __shared__ __align__(16) char smem[65536];

    const int tid  = threadIdx.x;
    const int lane = tid & 63;
    const int wv   = tid >> 6;
    const int lo   = lane & 15;
    const int hi   = lane >> 4;

    f32x4 acc[4][8];
#pragma unroll
    for (int mi = 0; mi < 4; ++mi)
#pragma unroll
        for (int ni = 0; ni < 8; ++ni) acc[mi][ni] = (f32x4){0.f, 0.f, 0.f, 0.f};

    const float* xslab = x + (size_t)b_ * 512 * 4096 + (size_t)(wh * 32 + rb * 2) * 64;
    const int tq = tid & 31;      // token-quad: tokens 4tq..4tq+3
    const int cs = tid >> 5;      // channel slab of 4: k = cs*4 .. +3 (within 32-k tile)
    const float* xpbase = xslab + (size_t)(cs * 4) * 4096 + tq * 4;

    f32x4 bregs[4];               // bregs[c] = 4 tokens of channel cs*4+c

#define K1_ISSUE_A(KT, BUF)                                                        \
    {                                                                              \
        const char* src_ = (const char*)wt + (size_t)(KT) * 16384;                 \
        char* dst_ = smem + (BUF) * 16384;                                         \
        _Pragma("unroll")                                                          \
        for (int r_ = 0; r_ < 4; ++r_) {                                           \
            int idx_ = (r_ * 256 + tid) * 16;                                      \
            gload_lds16(src_ + idx_, dst_ + idx_);                                 \
        }                                                                          \
    }
#define K1_LOAD_B(KT)                                                              \
    {                                                                              \
        const float* xp_ = xpbase + (size_t)(KT) * 32 * 4096;                      \
        _Pragma("unroll")                                                          \
        for (int c_ = 0; c_ < 4; ++c_) bregs[c_] = *(const f32x4*)(xp_ + (size_t)c_ * 4096); \
    }
#define K1_WRITE_B(BUF)                                                            \
    {                                                                              \
        char* lb_ = smem + 32768 + (BUF) * 10240;                                  \
        _Pragma("unroll")                                                          \
        for (int e_ = 0; e_ < 4; ++e_) {                                           \
            ushort4v u_ = {f2bf(bregs[0][e_]), f2bf(bregs[1][e_]),                 \
                           f2bf(bregs[2][e_]), f2bf(bregs[3][e_])};                \
            *(ushort4v*)(lb_ + (tq * 4 + e_) * 80 + cs * 8) = u_;                  \
        }                                                                          \
    }

    // prologue
    K1_ISSUE_A(0, 0);
    K1_LOAD_B(0);
    K1_WRITE_B(0);      // auto vmcnt(0): drains DMA(0) too (prologue only)
    K1_LOAD_B(1);
    LGKM0();
    __builtin_amdgcn_s_barrier();

    for (int kt = 0; kt < 16; ++kt) {
        const int b = kt & 1;
        // 1. DMA next A tile into lA[b^1]
        {
            const int ktn = (kt + 1 < 16) ? kt + 1 : 15;
            K1_ISSUE_A(ktn, b ^ 1);
        }
        // 2. compute current tile
        short8 af[4], bfr[8];
#pragma unroll
        for (int mi = 0; mi < 4; ++mi) {
            int base = (hi * 256 + wv * 64 + mi * 16 + lo) * 16;
            af[mi] = *(const short8*)(smem + b * 16384 + (base ^ ((hi & 3) << 4)));
        }
#pragma unroll
        for (int ni = 0; ni < 8; ++ni)
            bfr[ni] = *(const short8*)(smem + 32768 + b * 10240 + (ni * 16 + lo) * 80 + hi * 16);
        __builtin_amdgcn_s_setprio(1);
#pragma unroll
        for (int mi = 0; mi < 4; ++mi)
#pragma unroll
            for (int ni = 0; ni < 8; ++ni)
                acc[mi][ni] = __builtin_amdgcn_mfma_f32_16x16x32_bf16(af[mi], bfr[ni], acc[mi][ni], 0, 0, 0);
        __builtin_amdgcn_s_setprio(0);
        // 3. write next B (bregs 1 iter old; auto-wait = vmcnt(4), DMA stays in flight)
        K1_WRITE_B(b ^ 1);
        // 4. pin VMEM order across the next issue
        __builtin_amdgcn_sched_barrier(0);
        // 5. issue B loads for kt+2
        {
            const int ktn2 = (kt + 2 < 16) ? kt + 2 : 15;
            K1_LOAD_B(ktn2);
        }
        // 6. wait: 4 DMA done (4 younger B-loads in flight); publish lB writes
        VMCNT(4);
        LGKM0();
        __builtin_amdgcn_s_barrier();
    }
    VMCNT(0);

    // ---- per-token norm over c ----
    float part[8];
#pragma unroll
    for (int ni = 0; ni < 8; ++ni) {
        float s = 0.f;
#pragma unroll
        for (int mi = 0; mi < 4; ++mi)
#pragma unroll
            for (int r = 0; r < 4; ++r) s += acc[mi][ni][r] * acc[mi][ni][r];
        s += __shfl_xor(s, 16);
        s += __shfl_xor(s, 32);
        part[ni] = s;
    }
    if (hi == 0) {
#pragma unroll
        for (int ni = 0; ni < 8; ++ni)
            *(float*)(smem + 53248 + (wv * 128 + ni * 16 + lo) * 4) = part[ni];
    }
    __syncthreads();

    float inv[8];
#pragma unroll
    for (int ni = 0; ni < 8; ++ni) {
        const int tl = ni * 16 + lo;
        float s = *(const float*)(smem + 53248 + (0 * 128 + tl) * 4)
                + *(const float*)(smem + 53248 + (1 * 128 + tl) * 4)
                + *(const float*)(smem + 53248 + (2 * 128 + tl) * 4)
                + *(const float*)(smem + 53248 + (3 * 128 + tl) * 4);
        inv[ni] = 1.f / (sqrtf(s) + 1e-6f);
    }

    // stage normalized fp8 into sQ @smem[0..32K): row f (256B), byte c ^ ((f&3)<<4)
#pragma unroll
    for (int ni = 0; ni < 8; ++ni) {
        const int f    = ni * 16 + lo;
        const int swzf = (f & 3) << 4;
#pragma unroll
        for (int mi = 0; mi < 4; ++mi) {
            const int c = wv * 64 + mi * 16 + hi * 4;
            unsigned int u = pk_fp8x4(acc[mi][ni][0] * inv[ni], acc[mi][ni][1] * inv[ni],
                                      acc[mi][ni][2] * inv[ni], acc[mi][ni][3] * inv[ni]);
            *(unsigned int*)(smem + f * 256 + (c ^ swzf)) = u;
        }
    }
    __syncthreads();

    // coalesced store: 32 KB, 16B units; each row (256B) line-complete
#pragma unroll
    for (int it = 0; it < 8; ++it) {
        const int unit = it * 256 + tid;         // 0..2047
        const int f    = unit >> 4;
        const int c16  = (unit & 15) * 16;
        f32x4 d = *(const f32x4*)(smem + f * 256 + (c16 ^ ((f & 3) << 4)));
        const int ww  = (f >> 5) & 1;
        const int rho = f >> 6;
        const int rq  = rb * 64 + rho * 32 + (f & 31);
        char* qw = (char*)qn + (size_t)(winbase + ww) * (1024 * 256);
        *(f32x4*)(qw + (size_t)rq * 256 + (c16 ^ ((rq & 3) << 4))) = d;
    }
}

// ---------------- K2: S^T via fp8 MFMA, relu, packed bf16 P, PV (R13 verbatim) ----
// grid: 512 = 128 windows * 4 query-blocks (256 q); bid&127 = window (XCD swizzle).
__global__ __launch_bounds__(256, 2) void k2_attn(const unsigned char* __restrict__ qn,
                                                  const float* __restrict__ v,
                                                  float* __restrict__ out) {
    const int g   = blockIdx.x;
    const int win = g & 127;
    const int qb  = g >> 7;
    const int b_  = win >> 2;
    const int h0  = ((win >> 1) & 1) << 5;
    const int w0  = (win & 1) << 5;

    __shared__ __align__(16) char lK[64 * 256];             // fp8 key image, 16 KB
    __shared__ __align__(16) unsigned short lP[256][72];    // P bf16 [q][key], 36 KB
    __shared__ __align__(16) unsigned short lV[16][72];     // V^T [ch][key], row15 = ones

    const int tid  = threadIdx.x;
    const int lane = tid & 63;
    const int wv   = tid >> 6;
    const int lo   = lane & 15;
    const int hi   = lane >> 4;

    const unsigned char* qwin = qn + (size_t)win * (1024 * 256);
    const int qw0 = qb * 256 + wv * 64;

    long qa8[4][8];
#pragma unroll
    for (int mi = 0; mi < 4; ++mi) {
        const int rq = qw0 + mi * 16 + lo;
        const size_t swz = (size_t)((rq & 3) << 4);
#pragma unroll
        for (int kc = 0; kc < 8; ++kc)
            qa8[mi][kc] = *(const long*)(qwin + (((size_t)rq * 256 + kc * 32 + hi * 8) ^ swz));
    }

    f32x4 accout[4];
#pragma unroll
    for (int t = 0; t < 4; ++t) accout[t] = (f32x4){0.f, 0.f, 0.f, 0.f};

    const float* vbase = v + (size_t)b_ * 15 * 4096 + (size_t)h0 * 64 + w0;
    char* lKb = (char*)lK;
    char* lPb = (char*)&lP[0][0];
    char* lVb = (char*)&lV[0][0];

    for (int chk = 0; chk < 16; ++chk) {
        const int kbase = chk << 6;
        __syncthreads();
        {
            const char* src = (const char*)qwin + (size_t)kbase * 256;
#pragma unroll
            for (int r = 0; r < 4; ++r) {
                int idx = (r * 256 + tid) * 16;
                gload_lds16(src + idx, lKb + idx);
            }
        }
        {
            const int chn = tid & 15;
            const int kp  = tid >> 4;
            uint32x2 u;
            if (chn < 15) {
                int jk = kbase + kp * 4;
                const float* vp = vbase + (size_t)chn * 4096 + ((jk >> 5) * 64 + (jk & 31));
                f32x4 d = *(const f32x4*)vp;
                u[0] = pack2(d[0], d[1]);
                u[1] = pack2(d[2], d[3]);
            } else {
                u[0] = 0x3F803F80u;
                u[1] = 0x3F803F80u;
            }
            *(uint32x2*)(lVb + chn * 144 + kp * 8) = u;
        }
        __syncthreads();

#pragma unroll
        for (int ni = 0; ni < 4; ++ni) {
            f32x4 st[4];
#pragma unroll
            for (int mi = 0; mi < 4; ++mi) st[mi] = (f32x4){0.f, 0.f, 0.f, 0.f};
            __builtin_amdgcn_s_setprio(1);
#pragma unroll
            for (int kc = 0; kc < 8; ++kc) {
                const int row = ni * 16 + lo;
                const int off = ((row * 256) + kc * 32 + hi * 8) ^ ((row & 3) << 4);
                long kb = *(const long*)(lKb + off);
#pragma unroll
                for (int mi = 0; mi < 4; ++mi)
                    st[mi] = __builtin_amdgcn_mfma_f32_16x16x32_fp8_fp8(kb, qa8[mi][kc], st[mi], 0, 0, 0);
            }
            __builtin_amdgcn_s_setprio(0);
#pragma unroll
            for (int mi = 0; mi < 4; ++mi) {
                uint32x2 u;
                u[0] = pack2(fmaxf(st[mi][0], 0.f), fmaxf(st[mi][1], 0.f));
                u[1] = pack2(fmaxf(st[mi][2], 0.f), fmaxf(st[mi][3], 0.f));
                *(uint32x2*)(lPb + (wv * 64 + mi * 16 + lo) * 144 + ni * 32 + hi * 8) = u;
            }
        }

        __builtin_amdgcn_s_setprio(1);
#pragma unroll
        for (int t = 0; t < 4; ++t) {
#pragma unroll
            for (int ks = 0; ks < 2; ++ks) {
                short8 pa  = *(const short8*)(lPb + (wv * 64 + t * 16 + lo) * 144 + ks * 64 + hi * 16);
                short8 vbf = *(const short8*)(lVb + lo * 144 + ks * 64 + hi * 16);
                accout[t] = __builtin_amdgcn_mfma_f32_16x16x32_bf16(pa, vbf, accout[t], 0, 0, 0);
            }
        }
        __builtin_amdgcn_s_setprio(0);
    }

#pragma unroll
    for (int t = 0; t < 4; ++t) {
#pragma unroll
        for (int r = 0; r < 4; ++r) {
            float rs = __shfl(accout[t][r], (lane & 48) | 15);
            if (lo < 15) {
                int q = qw0 + t * 16 + hi * 4 + r;
                out[(size_t)(b_ * 15 + lo) * 4096 + (size_t)(h0 + (q >> 5)) * 64 + (w0 + (q & 31))] =
                    accout[t][r] / (rs + 1e-6f);
            }
        }
    }
}

extern "C" void kernel_launch(void* const* d_in, const int* in_sizes, int n_in,
                              void* d_out, int out_size, void* d_ws, size_t ws_size,
                              hipStream_t stream) {
    const float* x = (const float*)d_in[0];
    const float* v = (const float*)d_in[1];
    const float* w = (const float*)d_in[2];
    float* out = (float*)d_out;

    unsigned char*  qn = (unsigned char*)d_ws;                           // 32 MiB fp8 (swizzled)
    unsigned short* wt = (unsigned short*)((char*)d_ws + (size_t)32 * 1024 * 1024);  // 256 KiB tiled W

    k0_wt<<<64, 256, 0, stream>>>(w, wt);
    k1_qgemm<<<1024, 256, 0, stream>>>(x, wt, qn);
    k2_attn<<<512, 256, 0, stream>>>(qn, v, out);
}